// Round 6
// baseline (123.963 us; speedup 1.0000x reference)
//
#include <hip/hip_runtime.h>

#define B_ 2
#define N_ 512
#define C_ 128   // HIDDEN_DIM
#define A_ 64    // ATTN_DIM
#define H_ 128
#define TI 2     // query rows per attn block
#define TJ 128   // j-tile size
#define NT (N_/TJ)
#define THR 256

#define SC2L 2.885390081777927f     // 2*log2(e): exp(2x)=2^(SC2L*x)
#define NEG2LE -2.885390081777927f  // -2*log2(e)

// workspace layout (float offsets)
#define OFF_WET 0                           // We^T [A][H]
#define OFF_V   (OFF_WET + A_*H_)           // v = exp(2*h_o) [g][a]
#define OFF_US  (OFF_V  + B_*N_*A_)         // u = exp(2*h_1) [g][a]
#define OFF_XY  (OFF_US + B_*N_*A_)         // Xy [g][h]

__device__ __forceinline__ float fexp2(float x) { return __builtin_amdgcn_exp2f(x); }
__device__ __forceinline__ float frcp(float x)  { return __builtin_amdgcn_rcpf(x); }

// ---------------- kernel 1: projections -> u, v, Xy ----------------
__global__ __launch_bounds__(512) void proj_kernel(
    const float* __restrict__ X, const float* __restrict__ Wo,
    const float* __restrict__ W1, const float* __restrict__ Wy,
    const float* __restrict__ by, const float* __restrict__ We,
    float* __restrict__ ws) {
  __shared__ float xs[2][C_];
  int row0 = blockIdx.x * 2;
  int t = threadIdx.x;
  if (t < 2*C_) xs[t >> 7][t & 127] = X[(size_t)row0*C_ + t];
  __syncthreads();

  int rsub = t >> 8;
  int col  = t & 255;
  int g = row0 + rsub;

  const float* W;
  if (col < 64)       W = Wo + (size_t)col*C_;
  else if (col < 128) W = W1 + (size_t)(col - 64)*C_;
  else                W = Wy + (size_t)(col - 128)*C_;

  const float4* w4 = (const float4*)W;
  const float4* x4 = (const float4*)xs[rsub];
  float acc = 0.f;
  #pragma unroll 8
  for (int k = 0; k < C_/4; ++k) {
    float4 wv = w4[k];
    float4 xv = x4[k];
    acc = fmaf(wv.x, xv.x, acc);
    acc = fmaf(wv.y, xv.y, acc);
    acc = fmaf(wv.z, xv.z, acc);
    acc = fmaf(wv.w, xv.w, acc);
  }

  if (col < 64) {
    ws[OFF_V + (size_t)g*A_ + col] = fexp2(SC2L * acc);
  } else if (col < 128) {
    ws[OFF_US + (size_t)g*A_ + (col - 64)] = fexp2(SC2L * acc);
  } else {
    ws[OFF_XY + (size_t)g*H_ + (col - 128)] = acc + by[col - 128];
  }

  if (blockIdx.x == 0) {   // transpose We [H][A] -> [A][H]
    for (int k = t; k < A_*H_; k += 512) {
      int h = k >> 6, a = k & 63;
      ws[OFF_WET + a*H_ + h] = We[k];
    }
  }
}

// ---------------- kernel 2: fused attention, j-tiled through LDS ----------
// 512 blocks x 256 threads (4 waves), TI=2 rows, TJ=128 j-tile, 4 tiles.
// p_j = exp(-2*sum_a wphi_a*rcp(v*u+1)) is independent per j -> full fusion.
__global__ __launch_bounds__(THR, 4) void attn_kernel(
    const float* __restrict__ Wphi, const float* __restrict__ be,
    const float* __restrict__ ws, float* __restrict__ out) {
  __shared__ float4 u4[TJ][16];       // quad-swizzled u tile: u4[j][(a4+j)&15]  32 KB
  __shared__ float sc[TI][TJ];        // p for current tile
  __shared__ __align__(16) float pkv[TI][A_];
  __shared__ __align__(16) float pkw[A_];
  __shared__ float ebw[TI][2][A_];
  __shared__ float ebar[TI][A_];
  __shared__ float p1s[TI][2][H_];
  __shared__ float reds[TI][2];

  int t = threadIdx.x;
  int w = t >> 6, lane = t & 63;
  int blk = blockIdx.x;
  int b = blk >> 8;
  int i0 = (blk & 255) * TI;

  const float* vg   = ws + OFF_V + (size_t)(b*N_ + i0)*A_;
  const float4* usb = (const float4*)(ws + OFF_US + (size_t)(b*N_)*A_);
  const float* xyg  = ws + OFF_XY + (size_t)(b*N_)*H_;
  const float* wet  = ws + OFF_WET;

  if (t < TI*A_) { int r = t >> 6, a = t & 63; pkv[r][a] = vg[r*A_ + a]; }
  if (t < A_)    pkw[t] = Wphi[t];
  __syncthreads();

  // role indices
  int rA = t >> 7, jA = t & 127;          // Pass A: (row, j-in-tile)
  int rC = w >> 1, wiC = w & 1;           // Pass C: wave -> (row, j-parity); lane = a
  int gp = t >> 7, hh = t & 127;          // part1: (j-half, h)

  float vC = pkv[rC][lane];
  float lacc = 0.f, cacc = 0.f, d0 = 0.f, d1 = 0.f;

  for (int tile = 0; tile < NT; ++tile) {
    int j0 = tile * TJ;
    // ---- stage u tile into LDS (quad-swizzled)
    {
      const float4* src = usb + (size_t)j0 * (A_/4);
      #pragma unroll
      for (int i = 0; i < (TJ*A_/4)/THR; ++i) {
        int f = i*THR + t;                // float4 index within tile
        float4 val = src[f];
        int jj = f >> 4, a4 = f & 15;
        u4[jj][(a4 + jj) & 15] = val;
      }
    }
    __syncthreads();

    // ---- Pass A: thread (rA, jA): s' = sum_a wphi_a * rcp(v*u+1)
    {
      const float4* pv = (const float4*)&pkv[rA][0];
      const float4* pw = (const float4*)&pkw[0];
      float s = 0.f;
      #pragma unroll 4
      for (int a4 = 0; a4 < 16; ++a4) {
        float4 u = u4[jA][(a4 + jA) & 15];
        float4 v = pv[a4];
        float4 wq = pw[a4];
        s = fmaf(wq.x, frcp(fmaf(v.x, u.x, 1.f)), s);
        s = fmaf(wq.y, frcp(fmaf(v.y, u.y, 1.f)), s);
        s = fmaf(wq.z, frcp(fmaf(v.z, u.z, 1.f)), s);
        s = fmaf(wq.w, frcp(fmaf(v.w, u.w, 1.f)), s);
      }
      float p = fexp2(NEG2LE * s);       // softmax shift-invariance: no max needed
      sc[rA][jA] = p;
      lacc += p;
    }
    __syncthreads();

    // ---- Pass C: lane = a; wave covers j = jj*2 + wiC
    {
      #pragma unroll 4
      for (int jj = 0; jj < TJ/2; ++jj) {
        int j = jj*2 + wiC;
        int q = ((lane >> 2) + j) & 15;
        float u = ((const float*)&u4[j][q])[lane & 3];
        float pj = sc[rC][j];
        cacc = fmaf(pj, frcp(fmaf(vC, u, 1.f)), cacc);
      }
    }
    // ---- part1: thread (gp, hh): d_r += p_rj * Xy[j][hh]
    {
      const float* xq = xyg + (size_t)(j0 + gp*64)*H_ + hh;
      #pragma unroll 4
      for (int jc = 0; jc < 64; ++jc) {
        int j = gp*64 + jc;
        float xv = xq[(size_t)jc*H_];
        d0 = fmaf(sc[0][j], xv, d0);
        d1 = fmaf(sc[1][j], xv, d1);
      }
    }
    __syncthreads();   // protect u4/sc before next stage
  }

  // ---- write partials
  ebw[rC][wiC][lane] = cacc;
  p1s[0][gp][hh] = d0;
  p1s[1][gp][hh] = d1;
  #pragma unroll
  for (int m = 1; m < 64; m <<= 1) lacc += __shfl_xor(lacc, m);
  if (lane == 0) reds[rA][w & 1] = lacc;
  __syncthreads();

  // ---- ebar_un[r][a] = l_r - 2*sum(cacc)
  if (t < TI*A_) {
    int r = t >> 6, a = t & 63;
    float e = ebw[r][0][a] + ebw[r][1][a];
    float l = reds[r][0] + reds[r][1];
    ebar[r][a] = l - 2.0f*e;
  }
  __syncthreads();

  // ---- epilogue: out = (part1_un + We^T·ebar_un)/l + be
  {
    int r = t >> 7, h = t & 127;
    float acc = p1s[r][0][h] + p1s[r][1][h];
    float e2 = 0.f;
    #pragma unroll 8
    for (int a = 0; a < A_; ++a) e2 = fmaf(ebar[r][a], wet[a*H_ + h], e2);
    float l = reds[r][0] + reds[r][1];
    out[(size_t)(b*N_ + i0 + r)*H_ + h] = (acc + e2) * frcp(l) + be[h];
  }
}

extern "C" void kernel_launch(void* const* d_in, const int* in_sizes, int n_in,
                              void* d_out, int out_size, void* d_ws, size_t ws_size,
                              hipStream_t stream) {
  const float* X    = (const float*)d_in[0];
  const float* Wo   = (const float*)d_in[1];
  const float* W1   = (const float*)d_in[2];
  const float* Wphi = (const float*)d_in[3];
  const float* Wy   = (const float*)d_in[4];
  const float* by   = (const float*)d_in[5];
  const float* We   = (const float*)d_in[6];
  const float* be   = (const float*)d_in[7];
  float* out = (float*)d_out;
  float* ws  = (float*)d_ws;

  hipLaunchKernelGGL(proj_kernel, dim3(B_*N_/2), dim3(512), 0, stream,
                     X, Wo, W1, Wy, by, We, ws);
  hipLaunchKernelGGL(attn_kernel, dim3(B_*N_/TI), dim3(THR), 0, stream,
                     Wphi, be, ws, out);
}